// Round 4
// baseline (1485.984 us; speedup 1.0000x reference)
//
#include <hip/hip_runtime.h>
#include <math.h>

// B=4096, R=130, T=200, Q=64. f16 MFMA 16x16x32, fp32 accum/stats.
// R4: k_in is LDS-free (direct-global A-frags, clean+cvt in regs); BN partials
// reduced per-block in LDS then atomicAdd'd into [260][64] slot arrays;
// k_stats is a single block per stage.

typedef _Float16 f16;
typedef _Float16 f16x8 __attribute__((ext_vector_type(8)));
typedef float f32x4 __attribute__((ext_vector_type(4)));

#define MFMA16(a, b, c) __builtin_amdgcn_mfma_f32_16x16x32_f16((a), (b), (c), 0, 0, 0)

// ---------------- w_prep: weights -> f16 wf[80][224] (zero-pad K); zero stat slots
__global__ __launch_bounds__(256) void w_prep(
    const float* __restrict__ wq, const float* __restrict__ w1,
    f16* __restrict__ wf, float* __restrict__ slots)   // slots: 7*260*64 floats
{
  const int blk = blockIdx.x, tid = threadIdx.x;
  if (blk < 80) {
    if (tid < 224) {
      float v = 0.f;
      if (tid < 200) v = (blk < 64) ? wq[blk * 200 + tid] : w1[(blk - 64) * 200 + tid];
      wf[blk * 224 + tid] = (f16)v;
    }
  } else {
    int idx = (blk - 80) * 256 + tid;
    if (idx < 7 * 260 * 64) slots[idx] = 0.f;
  }
}

// ---------------- k_in: X(532480x200) @ wf^T -> qk f16, xw1 f16. No LDS.
__global__ __launch_bounds__(256) void k_in(
    const float* __restrict__ x, const f16* __restrict__ wf,
    const float* __restrict__ bq, f16* __restrict__ qk, f16* __restrict__ xw1)
{
  const int tid = threadIdx.x, lane = tid & 63, wid = tid >> 6;
  const int mrow = lane & 15, quad = lane >> 4;
  const size_t m0 = (size_t)blockIdx.x * 64;          // 8320 blocks
  const float* xr = x + (m0 + wid * 16 + mrow) * 200; // A-frag row for this lane
  const f16* wrow = wf + mrow * 224 + quad * 8;       // B-frags from global (L2-hot)
  f32x4 acc[5];
#pragma unroll
  for (int n = 0; n < 5; n++) acc[n] = (f32x4){0.f, 0.f, 0.f, 0.f};
#pragma unroll
  for (int s = 0; s < 6; s++) {                       // k = 0..191, all valid
    const int e0 = s * 32 + quad * 8;
    float4 u0 = *(const float4*)(xr + e0);
    float4 u1 = *(const float4*)(xr + e0 + 4);
    f16x8 af;
    af[0] = (f16)((u0.x != u0.x) ? 0.f : u0.x);
    af[1] = (f16)((u0.y != u0.y) ? 0.f : u0.y);
    af[2] = (f16)((u0.z != u0.z) ? 0.f : u0.z);
    af[3] = (f16)((u0.w != u0.w) ? 0.f : u0.w);
    af[4] = (f16)((u1.x != u1.x) ? 0.f : u1.x);
    af[5] = (f16)((u1.y != u1.y) ? 0.f : u1.y);
    af[6] = (f16)((u1.z != u1.z) ? 0.f : u1.z);
    af[7] = (f16)((u1.w != u1.w) ? 0.f : u1.w);
#pragma unroll
    for (int n = 0; n < 5; n++)
      acc[n] = MFMA16(af, *(const f16x8*)(wrow + n * 3584 + s * 32), acc[n]);
  }
  {                                                   // tail k = 192..223: only quad 0 valid
    f16x8 af;
#pragma unroll
    for (int j = 0; j < 8; j++) af[j] = (f16)0.f;
    if (quad == 0) {
      float4 u0 = *(const float4*)(xr + 192);
      float4 u1 = *(const float4*)(xr + 196);
      af[0] = (f16)((u0.x != u0.x) ? 0.f : u0.x);
      af[1] = (f16)((u0.y != u0.y) ? 0.f : u0.y);
      af[2] = (f16)((u0.z != u0.z) ? 0.f : u0.z);
      af[3] = (f16)((u0.w != u0.w) ? 0.f : u0.w);
      af[4] = (f16)((u1.x != u1.x) ? 0.f : u1.x);
      af[5] = (f16)((u1.y != u1.y) ? 0.f : u1.y);
      af[6] = (f16)((u1.z != u1.z) ? 0.f : u1.z);
      af[7] = (f16)((u1.w != u1.w) ? 0.f : u1.w);
    }
#pragma unroll
    for (int n = 0; n < 5; n++)
      acc[n] = MFMA16(af, *(const f16x8*)(wrow + n * 3584 + 192), acc[n]);
  }
  const size_t rbase = m0 + wid * 16;
#pragma unroll
  for (int n = 0; n < 4; n++) {                       // qk (+bq)
    int col = n * 16 + mrow;
    float bqv = bq[col];
#pragma unroll
    for (int i = 0; i < 4; i++)
      qk[(rbase + quad * 4 + i) * 64 + col] = (f16)(acc[n][i] + bqv);
  }
#pragma unroll
  for (int i = 0; i < 4; i++)                         // xw1, no bias (added post-A)
    xw1[(rbase + quad * 4 + i) * 16 + mrow] = (f16)acc[4][i];
}

// B-frag gather for the reshape-K matmul: B[k=q][n-col=s] = flat[q*130+s]
__device__ __forceinline__ void gather_bfrags(const f16* qf, int mrow, int quad,
                                              f16x8 bf[9][2])
{
#pragma unroll
  for (int n = 0; n < 9; n++) {
    const int s = n * 16 + mrow;
    const bool ok = (s < 130);
#pragma unroll
    for (int kh = 0; kh < 2; kh++) {
      f16x8 t;
#pragma unroll
      for (int j = 0; j < 8; j++) {
        int q = kh * 32 + quad * 8 + j;
        t[j] = ok ? qf[q * 130 + s] : (f16)0.f;
      }
      bf[n][kh] = t;
    }
  }
}

// ---------------- k_relstats: rel tiles via MFMA, BN partials -> LDS -> slots
__global__ __launch_bounds__(256) void k_relstats(
    const f16* __restrict__ qk, float* __restrict__ slots)
{
  __shared__ f16 qf[8320];
  __shared__ float stl[260];
  const int b = blockIdx.x, tid = threadIdx.x;
  const f16* qb = qk + (size_t)b * 8320;
  for (int i = tid; i < 1040; i += 256)
    *(f16x8*)&qf[i * 8] = *(const f16x8*)(qb + i * 8);
  for (int i = tid; i < 260; i += 256) stl[i] = 0.f;
  __syncthreads();
  const int lane = tid & 63, wv = tid >> 6, mrow = lane & 15, quad = lane >> 4;
  f16x8 bf[9][2];
  gather_bfrags(qf, mrow, quad, bf);
  for (int m = wv; m < 9; m += 4) {
    const f16* arow = qb + (m * 16 + mrow) * 64 + quad * 8;
    f16x8 af0 = *(const f16x8*)arow;
    f16x8 af1 = *(const f16x8*)(arow + 32);
    float p1[4] = {0, 0, 0, 0}, p2[4] = {0, 0, 0, 0};
#pragma unroll
    for (int n = 0; n < 9; n++) {
      f32x4 acc = (f32x4){0.f, 0.f, 0.f, 0.f};
      acc = MFMA16(af0, bf[n][0], acc);
      acc = MFMA16(af1, bf[n][1], acc);
#pragma unroll
      for (int i = 0; i < 4; i++) { float v = acc[i]; p1[i] += v; p2[i] += v * v; }
    }
#pragma unroll
    for (int i = 0; i < 4; i++)
#pragma unroll
      for (int msk = 1; msk <= 8; msk <<= 1) {
        p1[i] += __shfl_xor(p1[i], msk); p2[i] += __shfl_xor(p2[i], msk);
      }
    if (mrow == 0) {
#pragma unroll
      for (int i = 0; i < 4; i++) {
        int r = m * 16 + quad * 4 + i;
        if (r < 130) { atomicAdd(&stl[r], p1[i]); atomicAdd(&stl[130 + r], p2[i]); }
      }
    }
  }
  __syncthreads();
  const int slot = b & 63;
  for (int i = tid; i < 260; i += 256)
    atomicAdd(&slots[i * 64 + slot], stl[i]);
}

// ---------------- k_stats: reduce 64 slots -> affine a,c. Single block.
__global__ __launch_bounds__(256) void k_stats(
    const float* __restrict__ slots, const float* __restrict__ g,
    const float* __restrict__ beta, float invN, float* __restrict__ ac)
{
  __shared__ float tot[260];
  const int tid = threadIdx.x;
  for (int i = tid; i < 260; i += 256) {
    const float* p = slots + i * 64;
    float s = 0.f;
#pragma unroll
    for (int j = 0; j < 64; j++) s += p[j];
    tot[i] = s;
  }
  __syncthreads();
  if (tid < 130) {
    float mean = tot[tid] * invN;
    float var = tot[130 + tid] * invN - mean * mean;
    float a = g[tid] * rsqrtf(var + 1e-5f);
    ac[tid] = a;
    ac[130 + tid] = beta[tid] - mean * a;
  }
}

// ---------------- k_Asoft: rel (regs), affine, softmax, relu(x-thr), A -> f16
__global__ __launch_bounds__(256) void k_Asoft(
    const f16* __restrict__ qk, const float* __restrict__ ac0,
    const float* __restrict__ thrp, f16* __restrict__ A16)
{
  __shared__ f16 qf[8320];
  const int b = blockIdx.x, tid = threadIdx.x;
  const f16* qb = qk + (size_t)b * 8320;
  for (int i = tid; i < 1040; i += 256)
    *(f16x8*)&qf[i * 8] = *(const f16x8*)(qb + i * 8);
  __syncthreads();
  const float thr = *thrp;
  const int lane = tid & 63, wv = tid >> 6, mrow = lane & 15, quad = lane >> 4;
  f16x8 bf[9][2];
  gather_bfrags(qf, mrow, quad, bf);
  f16* Ab = A16 + (size_t)b * 17680;                  // row stride 136
  for (int m = wv; m < 9; m += 4) {
    float a4[4], c4[4];
#pragma unroll
    for (int i = 0; i < 4; i++) {
      int r = m * 16 + quad * 4 + i;
      a4[i] = (r < 130) ? ac0[r] : 0.f;
      c4[i] = (r < 130) ? ac0[130 + r] : 0.f;
    }
    const f16* arow = qb + (m * 16 + mrow) * 64 + quad * 8;
    f16x8 af0 = *(const f16x8*)arow;
    f16x8 af1 = *(const f16x8*)(arow + 32);
    f32x4 acc[9];
#pragma unroll
    for (int n = 0; n < 9; n++) {
      acc[n] = (f32x4){0.f, 0.f, 0.f, 0.f};
      acc[n] = MFMA16(af0, bf[n][0], acc[n]);
      acc[n] = MFMA16(af1, bf[n][1], acc[n]);
    }
    float mx[4] = {-3e38f, -3e38f, -3e38f, -3e38f}, sm[4] = {0, 0, 0, 0};
#pragma unroll
    for (int n = 0; n < 9; n++) {
      const bool valid = (n * 16 + mrow) < 130;
#pragma unroll
      for (int i = 0; i < 4; i++) {
        float v = a4[i] * acc[n][i] + c4[i];
        float ve = valid ? v : -3e38f;
        float nm = fmaxf(mx[i], ve);
        sm[i] = sm[i] * __expf(mx[i] - nm) + (valid ? __expf(v - nm) : 0.f);
        mx[i] = nm;
      }
    }
#pragma unroll
    for (int i = 0; i < 4; i++) {
#pragma unroll
      for (int msk = 1; msk <= 8; msk <<= 1) {
        float om = __shfl_xor(mx[i], msk), os = __shfl_xor(sm[i], msk);
        float nm = fmaxf(mx[i], om);
        sm[i] = sm[i] * __expf(mx[i] - nm) + os * __expf(om - nm);
        mx[i] = nm;
      }
      sm[i] = 1.f / sm[i];
    }
#pragma unroll
    for (int n = 0; n < 9; n++) {
      const int col = n * 16 + mrow;
#pragma unroll
      for (int i = 0; i < 4; i++) {
        int r = m * 16 + quad * 4 + i;
        if (r < 130) {
          if (col < 130) {
            float v = a4[i] * acc[n][i] + c4[i];
            Ab[r * 136 + col] = (f16)fmaxf(__expf(v - mx[i]) * sm[i] - thr, 0.f);
          } else if (col < 136) {
            Ab[r * 136 + col] = (f16)0.f;
          }
        }
      }
    }
  }
}

// ---------------- k_gcn: Z = A @ g + b; A-frags direct global; partials -> slots
template <int FI, int FO, bool RES, bool G1>
__global__ __launch_bounds__(256) void k_gcn(
    const f16* __restrict__ A16, const float* __restrict__ ZP,
    const float* __restrict__ ZQ, const f16* __restrict__ xw1,
    const float* __restrict__ acP, const float* __restrict__ acQ,
    const float* __restrict__ wmat, const float* __restrict__ bb,
    float* __restrict__ Zout, float* __restrict__ slots)
{
  __shared__ f16 gT[16 * 168];                        // [n][k], stride 168, zero-pad
  __shared__ float stl[260];
  const int b = blockIdx.x, tid = threadIdx.x;
  for (int i = tid; i < 1344; i += 256) ((float*)gT)[i] = 0.f;
  for (int i = tid; i < 260; i += 256) stl[i] = 0.f;
  __syncthreads();
  if constexpr (G1) {
    for (int i = tid; i < 2080; i += 256) {
      int s = i >> 4, f = i & 15;
      gT[f * 168 + s] = xw1[(size_t)b * 2080 + i];
    }
  } else {
    if (tid < 130) {
      const int r = tid;
      float h[FI];
      const float* zp = ZP + ((size_t)b * 130 + r) * FI;
      const float aP = acP[r], cP = acP[130 + r];
#pragma unroll
      for (int i = 0; i < FI; i++) h[i] = fmaxf(aP * zp[i] + cP, 0.f);
      if constexpr (RES) {
        const float* zq = ZQ + ((size_t)b * 130 + r) * FI;
        const float aQ = acQ[r], cQ = acQ[130 + r];
#pragma unroll
        for (int i = 0; i < FI; i++) h[i] += fmaxf(aQ * zq[i] + cQ, 0.f);
      }
#pragma unroll
      for (int k = 0; k < FO; k++) {
        float s = 0.f;
#pragma unroll
        for (int i = 0; i < FI; i++) s += h[i] * wmat[k * FI + i];
        gT[k * 168 + r] = (f16)s;                     // bias added post-A
      }
    }
  }
  __syncthreads();
  const int lane = tid & 63, wv = tid >> 6, mrow = lane & 15, quad = lane >> 4;
  f16x8 bfr[5];
#pragma unroll
  for (int kk = 0; kk < 5; kk++)
    bfr[kk] = *(const f16x8*)&gT[mrow * 168 + kk * 32 + quad * 8];
  const f16* Ab = A16 + (size_t)b * 17680;
  for (int m = wv; m < 9; m += 4) {
    const f16* arow = Ab + (m * 16 + mrow) * 136 + quad * 8;
    f32x4 acc = (f32x4){0.f, 0.f, 0.f, 0.f};
#pragma unroll
    for (int kk = 0; kk < 5; kk++)
      acc = MFMA16(*(const f16x8*)(arow + kk * 32), bfr[kk], acc);
    const int col = mrow;
    const float bk = (col < FO) ? bb[col] : 0.f;
    float p1[4], p2[4];
#pragma unroll
    for (int i = 0; i < 4; i++) {
      int r = m * 16 + quad * 4 + i;
      float v = (col < FO) ? acc[i] + bk : 0.f;
      if (col < FO && r < 130)
        Zout[((size_t)b * 130 + r) * FO + col] = v;
      p1[i] = v; p2[i] = v * v;
    }
#pragma unroll
    for (int i = 0; i < 4; i++)
#pragma unroll
      for (int msk = 1; msk <= 8; msk <<= 1) {
        p1[i] += __shfl_xor(p1[i], msk); p2[i] += __shfl_xor(p2[i], msk);
      }
    if (mrow == 0) {
#pragma unroll
      for (int i = 0; i < 4; i++) {
        int r = m * 16 + quad * 4 + i;
        if (r < 130) { atomicAdd(&stl[r], p1[i]); atomicAdd(&stl[130 + r], p2[i]); }
      }
    }
  }
  __syncthreads();
  const int slot = b & 63;
  for (int i = tid; i < 260; i += 256)
    atomicAdd(&slots[i * 64 + slot], stl[i]);
}

// ---------------- k_mlp
__global__ __launch_bounds__(256) void k_mlp(
    const float* __restrict__ Z5, const float* __restrict__ Z6,
    const float* __restrict__ ac5, const float* __restrict__ ac6,
    const float* __restrict__ wm, const float* __restrict__ bm, float* __restrict__ out)
{
  const int tid = threadIdx.x, lane = tid & 63, wv = tid >> 6;
  const int b = blockIdx.x * 4 + wv;
  const float* z5 = Z5 + (size_t)b * 260;
  const float* z6 = Z6 + (size_t)b * 260;
  float p0 = 0.f, p1 = 0.f;
#pragma unroll
  for (int j = 0; j < 5; j++) {
    int i = lane + 64 * j;
    if (i < 260) {
      int r = i >> 1;
      float h = fmaxf(ac6[r] * z6[i] + ac6[130 + r], 0.f)
              + fmaxf(ac5[r] * z5[i] + ac5[130 + r], 0.f);
      p0 += h * wm[i];
      p1 += h * wm[260 + i];
    }
  }
#pragma unroll
  for (int m = 1; m <= 32; m <<= 1) { p0 += __shfl_xor(p0, m); p1 += __shfl_xor(p1, m); }
  if (lane == 0) {
    out[(size_t)b * 2] = fmaxf(p0 + bm[0], 0.f);
    out[(size_t)b * 2 + 1] = fmaxf(p1 + bm[1], 0.f);
  }
}

extern "C" void kernel_launch(void* const* d_in, const int* in_sizes, int n_in,
                              void* d_out, int out_size, void* d_ws, size_t ws_size,
                              hipStream_t stream) {
  const float* X   = (const float*)d_in[0];
  const float* THR = (const float*)d_in[1];
  const float* WQ  = (const float*)d_in[2];
  const float* BQ  = (const float*)d_in[3];
  const float* GT  = (const float*)d_in[4];
  const float* BT  = (const float*)d_in[5];
  const float* W1 = (const float*)d_in[6];  const float* Bb1 = (const float*)d_in[7];
  const float* G1g = (const float*)d_in[8]; const float* BE1 = (const float*)d_in[9];
  const float* W2 = (const float*)d_in[10]; const float* Bb2 = (const float*)d_in[11];
  const float* G2 = (const float*)d_in[12]; const float* BE2 = (const float*)d_in[13];
  const float* W3 = (const float*)d_in[14]; const float* Bb3 = (const float*)d_in[15];
  const float* G3 = (const float*)d_in[16]; const float* BE3 = (const float*)d_in[17];
  const float* W4 = (const float*)d_in[18]; const float* Bb4 = (const float*)d_in[19];
  const float* G4 = (const float*)d_in[20]; const float* BE4 = (const float*)d_in[21];
  const float* W5 = (const float*)d_in[22]; const float* Bb5 = (const float*)d_in[23];
  const float* G5 = (const float*)d_in[24]; const float* BE5 = (const float*)d_in[25];
  const float* W6 = (const float*)d_in[26]; const float* Bb6 = (const float*)d_in[27];
  const float* G6 = (const float*)d_in[28]; const float* BE6 = (const float*)d_in[29];
  const float* WM = (const float*)d_in[30]; const float* BM = (const float*)d_in[31];

  float* ws = (float*)d_ws;
  // Workspace (float units), total ~81.06M floats = 324 MB.
  f16*   A16   = (f16*)ws;                    // 4096*130*136 halfs = 36,208,640 fl
  f16*   qk16  = (f16*)(ws + 36208640);       // 532480*64 halfs = 17,039,360 fl
  f16*   xw116 = (f16*)(ws + 53248000);       // 532480*16 halfs = 4,259,840 fl
  f16*   wf16  = (f16*)(ws + 57507840);       // 80*224 halfs = 8,960 fl
  float* Z1 = ws + 57516800;                  // 8,519,680
  float* Z2 = ws + 66036480;                  // 8,519,680
  float* Z3 = ws + 74556160;                  // 2,129,920
  float* Z4 = ws + 76686080;                  // 2,129,920
  float* Z5 = ws + 78816000;                  // 1,064,960
  float* Z6 = ws + 79880960;                  // 1,064,960
  float* sl = ws + 80945920;                  // 7*260*64 = 116,480 (stat slots)
  float* ac = ws + 81062400;                  // 7*260

  w_prep<<<80 + 455, 256, 0, stream>>>(WQ, W1, wf16, sl);
  k_in<<<8320, 256, 0, stream>>>(X, wf16, BQ, qk16, xw116);
  k_relstats<<<4096, 256, 0, stream>>>(qk16, sl);
  k_stats<<<1, 256, 0, stream>>>(sl, GT, BT, 1.f / 532480.f, ac);
  k_Asoft<<<4096, 256, 0, stream>>>(qk16, ac, THR, A16);
  k_gcn<16, 16, false, true><<<4096, 256, 0, stream>>>(A16, nullptr, nullptr, xw116,
      nullptr, nullptr, nullptr, Bb1, Z1, sl + 16640);
  k_stats<<<1, 256, 0, stream>>>(sl + 16640, G1g, BE1, 1.f / 65536.f, ac + 260);
  k_gcn<16, 16, false, false><<<4096, 256, 0, stream>>>(A16, Z1, nullptr, nullptr,
      ac + 260, nullptr, W2, Bb2, Z2, sl + 33280);
  k_stats<<<1, 256, 0, stream>>>(sl + 33280, G2, BE2, 1.f / 65536.f, ac + 520);
  k_gcn<16, 4, true, false><<<4096, 256, 0, stream>>>(A16, Z2, Z1, nullptr,
      ac + 520, ac + 260, W3, Bb3, Z3, sl + 49920);
  k_stats<<<1, 256, 0, stream>>>(sl + 49920, G3, BE3, 1.f / 16384.f, ac + 780);
  k_gcn<4, 4, false, false><<<4096, 256, 0, stream>>>(A16, Z3, nullptr, nullptr,
      ac + 780, nullptr, W4, Bb4, Z4, sl + 66560);
  k_stats<<<1, 256, 0, stream>>>(sl + 66560, G4, BE4, 1.f / 16384.f, ac + 1040);
  k_gcn<4, 2, true, false><<<4096, 256, 0, stream>>>(A16, Z4, Z3, nullptr,
      ac + 1040, ac + 780, W5, Bb5, Z5, sl + 83200);
  k_stats<<<1, 256, 0, stream>>>(sl + 83200, G5, BE5, 1.f / 8192.f, ac + 1300);
  k_gcn<2, 2, false, false><<<4096, 256, 0, stream>>>(A16, Z5, nullptr, nullptr,
      ac + 1300, nullptr, W6, Bb6, Z6, sl + 99840);
  k_stats<<<1, 256, 0, stream>>>(sl + 99840, G6, BE6, 1.f / 8192.f, ac + 1560);
  k_mlp<<<1024, 256, 0, stream>>>(Z5, Z6, ac + 1300, ac + 1560, WM, BM, (float*)d_out);
}

// Round 5
// 1218.496 us; speedup vs baseline: 1.2195x; 1.2195x over previous
//
#include <hip/hip_runtime.h>
#include <math.h>

// B=4096, R=130, T=200, Q=64. f16 MFMA 16x16x32, fp32 accum/stats.
// R5: stats via sp[260][4096] partials (no atomics, deterministic) + 130-block
// k_stats (R3-proven). k_in LDS-free (R4). GCN1 fused into k_Asoft via
// same-block global A re-read (R1-proven pattern).

typedef _Float16 f16;
typedef _Float16 f16x8 __attribute__((ext_vector_type(8)));
typedef float f32x4 __attribute__((ext_vector_type(4)));

#define MFMA16(a, b, c) __builtin_amdgcn_mfma_f32_16x16x32_f16((a), (b), (c), 0, 0, 0)

// ---------------- w_prep: weights -> f16 wf[80][224] (zero-pad K)
__global__ __launch_bounds__(256) void w_prep(
    const float* __restrict__ wq, const float* __restrict__ w1, f16* __restrict__ wf)
{
  const int f = blockIdx.x, k = threadIdx.x;   // 80 blocks
  if (k < 224) {
    float v = 0.f;
    if (k < 200) v = (f < 64) ? wq[f * 200 + k] : w1[(f - 64) * 200 + k];
    wf[f * 224 + k] = (f16)v;
  }
}

// ---------------- k_in: X(532480x200) @ wf^T -> qk f16, xw1 f16. No LDS.
__global__ __launch_bounds__(256) void k_in(
    const float* __restrict__ x, const f16* __restrict__ wf,
    const float* __restrict__ bq, f16* __restrict__ qk, f16* __restrict__ xw1)
{
  const int tid = threadIdx.x, lane = tid & 63, wid = tid >> 6;
  const int mrow = lane & 15, quad = lane >> 4;
  const size_t m0 = (size_t)blockIdx.x * 64;          // 8320 blocks
  const float* xr = x + (m0 + wid * 16 + mrow) * 200;
  const f16* wrow = wf + mrow * 224 + quad * 8;
  f32x4 acc[5];
#pragma unroll
  for (int n = 0; n < 5; n++) acc[n] = (f32x4){0.f, 0.f, 0.f, 0.f};
#pragma unroll
  for (int s = 0; s < 6; s++) {                       // k = 0..191
    const int e0 = s * 32 + quad * 8;
    float4 u0 = *(const float4*)(xr + e0);
    float4 u1 = *(const float4*)(xr + e0 + 4);
    f16x8 af;
    af[0] = (f16)((u0.x != u0.x) ? 0.f : u0.x);
    af[1] = (f16)((u0.y != u0.y) ? 0.f : u0.y);
    af[2] = (f16)((u0.z != u0.z) ? 0.f : u0.z);
    af[3] = (f16)((u0.w != u0.w) ? 0.f : u0.w);
    af[4] = (f16)((u1.x != u1.x) ? 0.f : u1.x);
    af[5] = (f16)((u1.y != u1.y) ? 0.f : u1.y);
    af[6] = (f16)((u1.z != u1.z) ? 0.f : u1.z);
    af[7] = (f16)((u1.w != u1.w) ? 0.f : u1.w);
#pragma unroll
    for (int n = 0; n < 5; n++)
      acc[n] = MFMA16(af, *(const f16x8*)(wrow + n * 3584 + s * 32), acc[n]);
  }
  {                                                   // tail k = 192..223: quad 0 only
    f16x8 af;
#pragma unroll
    for (int j = 0; j < 8; j++) af[j] = (f16)0.f;
    if (quad == 0) {
      float4 u0 = *(const float4*)(xr + 192);
      float4 u1 = *(const float4*)(xr + 196);
      af[0] = (f16)((u0.x != u0.x) ? 0.f : u0.x);
      af[1] = (f16)((u0.y != u0.y) ? 0.f : u0.y);
      af[2] = (f16)((u0.z != u0.z) ? 0.f : u0.z);
      af[3] = (f16)((u0.w != u0.w) ? 0.f : u0.w);
      af[4] = (f16)((u1.x != u1.x) ? 0.f : u1.x);
      af[5] = (f16)((u1.y != u1.y) ? 0.f : u1.y);
      af[6] = (f16)((u1.z != u1.z) ? 0.f : u1.z);
      af[7] = (f16)((u1.w != u1.w) ? 0.f : u1.w);
    }
#pragma unroll
    for (int n = 0; n < 5; n++)
      acc[n] = MFMA16(af, *(const f16x8*)(wrow + n * 3584 + 192), acc[n]);
  }
  const size_t rbase = m0 + wid * 16;
#pragma unroll
  for (int n = 0; n < 4; n++) {
    int col = n * 16 + mrow;
    float bqv = bq[col];
#pragma unroll
    for (int i = 0; i < 4; i++)
      qk[(rbase + quad * 4 + i) * 64 + col] = (f16)(acc[n][i] + bqv);
  }
#pragma unroll
  for (int i = 0; i < 4; i++)
    xw1[(rbase + quad * 4 + i) * 16 + mrow] = (f16)acc[4][i];
}

// B-frag gather for the reshape-K matmul: B[k=q][n-col=s] = flat[q*130+s]
__device__ __forceinline__ void gather_bfrags(const f16* qf, int mrow, int quad,
                                              f16x8 bf[9][2])
{
#pragma unroll
  for (int n = 0; n < 9; n++) {
    const int s = n * 16 + mrow;
    const bool ok = (s < 130);
#pragma unroll
    for (int kh = 0; kh < 2; kh++) {
      f16x8 t;
#pragma unroll
      for (int j = 0; j < 8; j++) {
        int q = kh * 32 + quad * 8 + j;
        t[j] = ok ? qf[q * 130 + s] : (f16)0.f;
      }
      bf[n][kh] = t;
    }
  }
}

// ---------------- k_relstats: rel tiles via MFMA, BN partials -> sp (no atomics)
__global__ __launch_bounds__(256) void k_relstats(
    const f16* __restrict__ qk, float* __restrict__ sp)
{
  __shared__ f16 qf[8320];
  const int b = blockIdx.x, tid = threadIdx.x;
  const f16* qb = qk + (size_t)b * 8320;
  for (int i = tid; i < 1040; i += 256)
    *(f16x8*)&qf[i * 8] = *(const f16x8*)(qb + i * 8);
  __syncthreads();
  const int lane = tid & 63, wv = tid >> 6, mrow = lane & 15, quad = lane >> 4;
  f16x8 bf[9][2];
  gather_bfrags(qf, mrow, quad, bf);
  for (int m = wv; m < 9; m += 4) {
    const f16* arow = qb + (m * 16 + mrow) * 64 + quad * 8;
    f16x8 af0 = *(const f16x8*)arow;
    f16x8 af1 = *(const f16x8*)(arow + 32);
    float p1[4] = {0, 0, 0, 0}, p2[4] = {0, 0, 0, 0};
#pragma unroll
    for (int n = 0; n < 9; n++) {
      f32x4 acc = (f32x4){0.f, 0.f, 0.f, 0.f};
      acc = MFMA16(af0, bf[n][0], acc);
      acc = MFMA16(af1, bf[n][1], acc);
#pragma unroll
      for (int i = 0; i < 4; i++) { float v = acc[i]; p1[i] += v; p2[i] += v * v; }
    }
#pragma unroll
    for (int i = 0; i < 4; i++)
#pragma unroll
      for (int msk = 1; msk <= 8; msk <<= 1) {
        p1[i] += __shfl_xor(p1[i], msk); p2[i] += __shfl_xor(p2[i], msk);
      }
    if (mrow == 0) {
#pragma unroll
      for (int i = 0; i < 4; i++) {
        int r = m * 16 + quad * 4 + i;
        if (r < 130) {
          sp[(size_t)r * 4096 + b] = p1[i];
          sp[130 * 4096 + (size_t)r * 4096 + b] = p2[i];
        }
      }
    }
  }
}

// ---------------- k_stats: reduce sp partials -> affine a,c (130 blocks)
__global__ __launch_bounds__(256) void k_stats(
    const float* __restrict__ sp, const float* __restrict__ g,
    const float* __restrict__ beta, float invN, float* __restrict__ ac)
{
  const int r = blockIdx.x, tid = threadIdx.x;
  float s1 = 0.f, s2 = 0.f;
  const float* p1 = sp + (size_t)r * 4096;
  const float* p2 = sp + 130 * 4096 + (size_t)r * 4096;
  for (int j = tid; j < 4096; j += 256) { s1 += p1[j]; s2 += p2[j]; }
#pragma unroll
  for (int m = 1; m <= 32; m <<= 1) { s1 += __shfl_xor(s1, m); s2 += __shfl_xor(s2, m); }
  __shared__ float r1[4], r2[4];
  if ((tid & 63) == 0) { r1[tid >> 6] = s1; r2[tid >> 6] = s2; }
  __syncthreads();
  if (tid == 0) {
    float S1 = r1[0] + r1[1] + r1[2] + r1[3];
    float S2 = r2[0] + r2[1] + r2[2] + r2[3];
    float mean = S1 * invN;
    float var = S2 * invN - mean * mean;
    float a = g[r] * rsqrtf(var + 1e-5f);
    ac[r] = a;
    ac[130 + r] = beta[r] - mean * a;
  }
}

// ---------------- k_Asoft: rel -> affine -> softmax -> relu(x-thr) -> A f16;
// then fused GCN1: Z1 = A @ xw1 + b1 (A re-read from L2-hot global), stats -> sp
__global__ __launch_bounds__(256) void k_Asoft(
    const f16* __restrict__ qk, const float* __restrict__ ac0,
    const float* __restrict__ thrp, const f16* __restrict__ xw1,
    const float* __restrict__ b1, f16* __restrict__ A16,
    float* __restrict__ Z1, float* __restrict__ sp)
{
  __shared__ f16 qf[8320];
  __shared__ f16 gT[16 * 168];                        // xw1^T, stride 168, zero-pad
  const int b = blockIdx.x, tid = threadIdx.x;
  const f16* qb = qk + (size_t)b * 8320;
  for (int i = tid; i < 1040; i += 256)
    *(f16x8*)&qf[i * 8] = *(const f16x8*)(qb + i * 8);
  for (int i = tid; i < 1344; i += 256) ((float*)gT)[i] = 0.f;
  __syncthreads();
  for (int i = tid; i < 2080; i += 256) {             // gT[f][s] = xw1[b][s][f]
    int s = i >> 4, f = i & 15;
    gT[f * 168 + s] = xw1[(size_t)b * 2080 + i];
  }
  const float thr = *thrp;
  const int lane = tid & 63, wv = tid >> 6, mrow = lane & 15, quad = lane >> 4;
  f16x8 bf[9][2];
  gather_bfrags(qf, mrow, quad, bf);
  f16* Ab = A16 + (size_t)b * 17680;                  // row stride 136
  for (int m = wv; m < 9; m += 4) {
    float a4[4], c4[4];
#pragma unroll
    for (int i = 0; i < 4; i++) {
      int r = m * 16 + quad * 4 + i;
      a4[i] = (r < 130) ? ac0[r] : 0.f;
      c4[i] = (r < 130) ? ac0[130 + r] : 0.f;
    }
    const f16* arow = qb + (m * 16 + mrow) * 64 + quad * 8;
    f16x8 af0 = *(const f16x8*)arow;
    f16x8 af1 = *(const f16x8*)(arow + 32);
    f32x4 acc[9];
#pragma unroll
    for (int n = 0; n < 9; n++) {
      acc[n] = (f32x4){0.f, 0.f, 0.f, 0.f};
      acc[n] = MFMA16(af0, bf[n][0], acc[n]);
      acc[n] = MFMA16(af1, bf[n][1], acc[n]);
    }
    float mx[4] = {-3e38f, -3e38f, -3e38f, -3e38f}, sm[4] = {0, 0, 0, 0};
#pragma unroll
    for (int n = 0; n < 9; n++) {
      const bool valid = (n * 16 + mrow) < 130;
#pragma unroll
      for (int i = 0; i < 4; i++) {
        float v = a4[i] * acc[n][i] + c4[i];
        float ve = valid ? v : -3e38f;
        float nm = fmaxf(mx[i], ve);
        sm[i] = sm[i] * __expf(mx[i] - nm) + (valid ? __expf(v - nm) : 0.f);
        mx[i] = nm;
      }
    }
#pragma unroll
    for (int i = 0; i < 4; i++) {
#pragma unroll
      for (int msk = 1; msk <= 8; msk <<= 1) {
        float om = __shfl_xor(mx[i], msk), os = __shfl_xor(sm[i], msk);
        float nm = fmaxf(mx[i], om);
        sm[i] = sm[i] * __expf(mx[i] - nm) + os * __expf(om - nm);
        mx[i] = nm;
      }
      sm[i] = 1.f / sm[i];
    }
#pragma unroll
    for (int n = 0; n < 9; n++) {
      const int col = n * 16 + mrow;
#pragma unroll
      for (int i = 0; i < 4; i++) {
        int r = m * 16 + quad * 4 + i;
        if (r < 130) {
          if (col < 130) {
            float v = a4[i] * acc[n][i] + c4[i];
            Ab[r * 136 + col] = (f16)fmaxf(__expf(v - mx[i]) * sm[i] - thr, 0.f);
          } else if (col < 136) {
            Ab[r * 136 + col] = (f16)0.f;
          }
        }
      }
    }
  }
  __threadfence_block();
  __syncthreads();
  // ---- fused GCN1: Z1 = A @ xw1 + b1 (A hot in L1/L2 from this block's writes)
  f16x8 bfr[5];
#pragma unroll
  for (int kk = 0; kk < 5; kk++)
    bfr[kk] = *(const f16x8*)&gT[mrow * 168 + kk * 32 + quad * 8];
  for (int m = wv; m < 9; m += 4) {
    const f16* arow = Ab + (m * 16 + mrow) * 136 + quad * 8;
    f32x4 acc = (f32x4){0.f, 0.f, 0.f, 0.f};
#pragma unroll
    for (int kk = 0; kk < 5; kk++)
      acc = MFMA16(*(const f16x8*)(arow + kk * 32), bfr[kk], acc);
    const float bk = b1[mrow];
    float p1[4], p2[4];
#pragma unroll
    for (int i = 0; i < 4; i++) {
      int r = m * 16 + quad * 4 + i;
      float v = acc[i] + bk;
      if (r < 130)
        Z1[((size_t)b * 130 + r) * 16 + mrow] = v;
      p1[i] = v; p2[i] = v * v;
    }
#pragma unroll
    for (int i = 0; i < 4; i++)
#pragma unroll
      for (int msk = 1; msk <= 8; msk <<= 1) {
        p1[i] += __shfl_xor(p1[i], msk); p2[i] += __shfl_xor(p2[i], msk);
      }
    if (mrow == 0) {
#pragma unroll
      for (int i = 0; i < 4; i++) {
        int r = m * 16 + quad * 4 + i;
        if (r < 130) {
          sp[(size_t)r * 4096 + b] = p1[i];
          sp[130 * 4096 + (size_t)r * 4096 + b] = p2[i];
        }
      }
    }
  }
}

// ---------------- k_gcn: Z = A @ g + b; A-frags direct global; partials -> sp
template <int FI, int FO, bool RES>
__global__ __launch_bounds__(256) void k_gcn(
    const f16* __restrict__ A16, const float* __restrict__ ZP,
    const float* __restrict__ ZQ,
    const float* __restrict__ acP, const float* __restrict__ acQ,
    const float* __restrict__ wmat, const float* __restrict__ bb,
    float* __restrict__ Zout, float* __restrict__ sp)
{
  __shared__ f16 gT[16 * 168];
  const int b = blockIdx.x, tid = threadIdx.x;
  for (int i = tid; i < 1344; i += 256) ((float*)gT)[i] = 0.f;
  __syncthreads();
  if (tid < 130) {
    const int r = tid;
    float h[FI];
    const float* zp = ZP + ((size_t)b * 130 + r) * FI;
    const float aP = acP[r], cP = acP[130 + r];
#pragma unroll
    for (int i = 0; i < FI; i++) h[i] = fmaxf(aP * zp[i] + cP, 0.f);
    if constexpr (RES) {
      const float* zq = ZQ + ((size_t)b * 130 + r) * FI;
      const float aQ = acQ[r], cQ = acQ[130 + r];
#pragma unroll
      for (int i = 0; i < FI; i++) h[i] += fmaxf(aQ * zq[i] + cQ, 0.f);
    }
#pragma unroll
    for (int k = 0; k < FO; k++) {
      float s = 0.f;
#pragma unroll
      for (int i = 0; i < FI; i++) s += h[i] * wmat[k * FI + i];
      gT[k * 168 + r] = (f16)s;                       // bias added post-A
    }
  }
  __syncthreads();
  const int lane = tid & 63, wv = tid >> 6, mrow = lane & 15, quad = lane >> 4;
  f16x8 bfr[5];
#pragma unroll
  for (int kk = 0; kk < 5; kk++)
    bfr[kk] = *(const f16x8*)&gT[mrow * 168 + kk * 32 + quad * 8];
  const f16* Ab = A16 + (size_t)b * 17680;
  for (int m = wv; m < 9; m += 4) {
    const f16* arow = Ab + (m * 16 + mrow) * 136 + quad * 8;
    f32x4 acc = (f32x4){0.f, 0.f, 0.f, 0.f};
#pragma unroll
    for (int kk = 0; kk < 5; kk++)
      acc = MFMA16(*(const f16x8*)(arow + kk * 32), bfr[kk], acc);
    const int col = mrow;
    const float bk = (col < FO) ? bb[col] : 0.f;
    float p1[4], p2[4];
#pragma unroll
    for (int i = 0; i < 4; i++) {
      int r = m * 16 + quad * 4 + i;
      float v = (col < FO) ? acc[i] + bk : 0.f;
      if (col < FO && r < 130)
        Zout[((size_t)b * 130 + r) * FO + col] = v;
      p1[i] = v; p2[i] = v * v;
    }
#pragma unroll
    for (int i = 0; i < 4; i++)
#pragma unroll
      for (int msk = 1; msk <= 8; msk <<= 1) {
        p1[i] += __shfl_xor(p1[i], msk); p2[i] += __shfl_xor(p2[i], msk);
      }
    if (mrow == 0) {
#pragma unroll
      for (int i = 0; i < 4; i++) {
        int r = m * 16 + quad * 4 + i;
        if (r < 130) {
          sp[(size_t)r * 4096 + b] = p1[i];
          sp[130 * 4096 + (size_t)r * 4096 + b] = p2[i];
        }
      }
    }
  }
}

// ---------------- k_mlp
__global__ __launch_bounds__(256) void k_mlp(
    const float* __restrict__ Z5, const float* __restrict__ Z6,
    const float* __restrict__ ac5, const float* __restrict__ ac6,
    const float* __restrict__ wm, const float* __restrict__ bm, float* __restrict__ out)
{
  const int tid = threadIdx.x, lane = tid & 63, wv = tid >> 6;
  const int b = blockIdx.x * 4 + wv;
  const float* z5 = Z5 + (size_t)b * 260;
  const float* z6 = Z6 + (size_t)b * 260;
  float p0 = 0.f, p1 = 0.f;
#pragma unroll
  for (int j = 0; j < 5; j++) {
    int i = lane + 64 * j;
    if (i < 260) {
      int r = i >> 1;
      float h = fmaxf(ac6[r] * z6[i] + ac6[130 + r], 0.f)
              + fmaxf(ac5[r] * z5[i] + ac5[130 + r], 0.f);
      p0 += h * wm[i];
      p1 += h * wm[260 + i];
    }
  }
#pragma unroll
  for (int m = 1; m <= 32; m <<= 1) { p0 += __shfl_xor(p0, m); p1 += __shfl_xor(p1, m); }
  if (lane == 0) {
    out[(size_t)b * 2] = fmaxf(p0 + bm[0], 0.f);
    out[(size_t)b * 2 + 1] = fmaxf(p1 + bm[1], 0.f);
  }
}

extern "C" void kernel_launch(void* const* d_in, const int* in_sizes, int n_in,
                              void* d_out, int out_size, void* d_ws, size_t ws_size,
                              hipStream_t stream) {
  const float* X   = (const float*)d_in[0];
  const float* THR = (const float*)d_in[1];
  const float* WQ  = (const float*)d_in[2];
  const float* BQ  = (const float*)d_in[3];
  const float* GT  = (const float*)d_in[4];
  const float* BT  = (const float*)d_in[5];
  const float* W1 = (const float*)d_in[6];  const float* Bb1 = (const float*)d_in[7];
  const float* G1g = (const float*)d_in[8]; const float* BE1 = (const float*)d_in[9];
  const float* W2 = (const float*)d_in[10]; const float* Bb2 = (const float*)d_in[11];
  const float* G2 = (const float*)d_in[12]; const float* BE2 = (const float*)d_in[13];
  const float* W3 = (const float*)d_in[14]; const float* Bb3 = (const float*)d_in[15];
  const float* G3 = (const float*)d_in[16]; const float* BE3 = (const float*)d_in[17];
  const float* W4 = (const float*)d_in[18]; const float* Bb4 = (const float*)d_in[19];
  const float* G4 = (const float*)d_in[20]; const float* BE4 = (const float*)d_in[21];
  const float* W5 = (const float*)d_in[22]; const float* Bb5 = (const float*)d_in[23];
  const float* G5 = (const float*)d_in[24]; const float* BE5 = (const float*)d_in[25];
  const float* W6 = (const float*)d_in[26]; const float* Bb6 = (const float*)d_in[27];
  const float* G6 = (const float*)d_in[28]; const float* BE6 = (const float*)d_in[29];
  const float* WM = (const float*)d_in[30]; const float* BM = (const float*)d_in[31];

  float* ws = (float*)d_ws;
  // Workspace (float units), ~82.0M floats = 328 MB.
  f16*   A16   = (f16*)ws;                    // 4096*130*136 halfs
  f16*   qk16  = (f16*)(ws + 36208640);       // 532480*64 halfs
  f16*   xw116 = (f16*)(ws + 53248000);       // 532480*16 halfs
  f16*   wf16  = (f16*)(ws + 57507840);       // 80*224 halfs
  float* Z1 = ws + 57516800;
  float* Z2 = ws + 66036480;
  float* Z3 = ws + 74556160;
  float* Z4 = ws + 76686080;
  float* Z5 = ws + 78816000;
  float* Z6 = ws + 79880960;
  float* sp = ws + 80945920;                  // 2*130*4096
  float* ac = ws + 82010880;                  // 7*260

  w_prep<<<80, 256, 0, stream>>>(WQ, W1, wf16);
  k_in<<<8320, 256, 0, stream>>>(X, wf16, BQ, qk16, xw116);
  k_relstats<<<4096, 256, 0, stream>>>(qk16, sp);
  k_stats<<<130, 256, 0, stream>>>(sp, GT, BT, 1.f / 532480.f, ac);
  k_Asoft<<<4096, 256, 0, stream>>>(qk16, ac, THR, xw116, Bb1, A16, Z1, sp);
  k_stats<<<130, 256, 0, stream>>>(sp, G1g, BE1, 1.f / 65536.f, ac + 260);
  k_gcn<16, 16, false><<<4096, 256, 0, stream>>>(A16, Z1, nullptr,
      ac + 260, nullptr, W2, Bb2, Z2, sp);
  k_stats<<<130, 256, 0, stream>>>(sp, G2, BE2, 1.f / 65536.f, ac + 520);
  k_gcn<16, 4, true><<<4096, 256, 0, stream>>>(A16, Z2, Z1,
      ac + 520, ac + 260, W3, Bb3, Z3, sp);
  k_stats<<<130, 256, 0, stream>>>(sp, G3, BE3, 1.f / 16384.f, ac + 780);
  k_gcn<4, 4, false><<<4096, 256, 0, stream>>>(A16, Z3, nullptr,
      ac + 780, nullptr, W4, Bb4, Z4, sp);
  k_stats<<<130, 256, 0, stream>>>(sp, G4, BE4, 1.f / 16384.f, ac + 1040);
  k_gcn<4, 2, true><<<4096, 256, 0, stream>>>(A16, Z4, Z3,
      ac + 1040, ac + 780, W5, Bb5, Z5, sp);
  k_stats<<<130, 256, 0, stream>>>(sp, G5, BE5, 1.f / 8192.f, ac + 1300);
  k_gcn<2, 2, false><<<4096, 256, 0, stream>>>(A16, Z5, nullptr,
      ac + 1300, nullptr, W6, Bb6, Z6, sp);
  k_stats<<<130, 256, 0, stream>>>(sp, G6, BE6, 1.f / 8192.f, ac + 1560);
  k_mlp<<<1024, 256, 0, stream>>>(Z5, Z6, ac + 1300, ac + 1560, WM, BM, (float*)d_out);
}